// Round 1
// baseline (1285.123 us; speedup 1.0000x reference)
//
#include <hip/hip_runtime.h>
#include <math.h>

#define N_NODES 50000
#define N_EDGES 500000
#define EMBED   128
#define RBF_DIM 16
#define N_OUT   12

#define EK_ITERS 4          // edge groups (of 8) per block
#define TILE_N   64         // nodes per block in node kernel
#define DCHUNK   64         // d-rows of W^T staged at a time
#define SPAD     (EMBED + 4)  // padded LDS row stride (floats)

__device__ __forceinline__ float ssp(float x) {
    // softplus(x) - log(2), numerically stable
    return fmaxf(x, 0.f) + log1pf(expf(-fabsf(x))) - 0.6931471805599453f;
}

// ---------------- Kernel 1: edge messages + scatter-add ----------------
// block = 256 threads = 8 edges x 32 lanes; each lane owns 4 channels.
__global__ __launch_bounds__(256) void edge_kernel(
    const float* __restrict__ rbf,   // [E,16]
    const float* __restrict__ m,     // [E,128]
    const int*   __restrict__ dst,   // [E] (row 1 of atom_edge_index)
    const float* __restrict__ wr,    // [128,16] (torch convention [out,in])
    float* __restrict__ acc)         // [N,128], zero-initialized
{
    __shared__ float s_rbf[8][RBF_DIM];
    const int tid  = threadIdx.x;
    const int lane = tid & 31;
    const int esub = tid >> 5;
    const int c0   = lane * 4;

    // W rows c0..c0+3 into registers (64 VGPR) — reused across all edges
    float w[4][RBF_DIM];
    #pragma unroll
    for (int i = 0; i < 4; ++i) {
        const float4* wp = (const float4*)(wr + (c0 + i) * RBF_DIM);
        #pragma unroll
        for (int q = 0; q < 4; ++q) {
            float4 v = wp[q];
            w[i][q*4+0] = v.x; w[i][q*4+1] = v.y;
            w[i][q*4+2] = v.z; w[i][q*4+3] = v.w;
        }
    }

    long e0 = (long)blockIdx.x * (8 * EK_ITERS);
    for (int it = 0; it < EK_ITERS; ++it, e0 += 8) {
        __syncthreads();
        if (tid < 8 * RBF_DIM) {
            // coalesced 512B: rbf rows for the 8 edges of this group
            s_rbf[tid >> 4][tid & 15] = rbf[e0 * RBF_DIM + tid];
        }
        __syncthreads();

        const long e = e0 + esub;
        float rv[RBF_DIM];
        #pragma unroll
        for (int r = 0; r < RBF_DIM; ++r) rv[r] = s_rbf[esub][r];

        float4 mv = *(const float4*)(m + e * EMBED + c0);

        float o0 = 0.f, o1 = 0.f, o2 = 0.f, o3 = 0.f;
        #pragma unroll
        for (int r = 0; r < RBF_DIM; ++r) {
            o0 = fmaf(rv[r], w[0][r], o0);
            o1 = fmaf(rv[r], w[1][r], o1);
            o2 = fmaf(rv[r], w[2][r], o2);
            o3 = fmaf(rv[r], w[3][r], o3);
        }

        const int d = dst[e];
        float* ap = acc + (long)d * EMBED + c0;
        atomicAdd(ap + 0, o0 * mv.x);
        atomicAdd(ap + 1, o1 * mv.y);
        atomicAdd(ap + 2, o2 * mv.z);
        atomicAdd(ap + 3, o3 * mv.w);
    }
}

// ---------------- Kernel 2: fused 3x dense(ssp) + output ----------------
// block = 256 threads; tile = 64 nodes.
// thread (cg = tid&15, ng = tid>>4) owns 4 nodes x 8 channels:
//   nodes n0..n0+3 (n0 = 4*ng); channels {4cg..4cg+3} U {64+4cg..64+4cg+3}
// (split channel halves keep the LDS float4 reads ~conflict-free)
__global__ __launch_bounds__(256) void node_kernel(
    const float* __restrict__ acc,   // [N,128]
    const float* __restrict__ dw,    // [3,128,128]
    const float* __restrict__ db,    // [3,128]
    const float* __restrict__ ow,    // [12,128]
    float* __restrict__ out)         // [N,12]
{
    __shared__ float s_in[TILE_N][SPAD];   // ~33.8 KB
    __shared__ float s_w[DCHUNK][SPAD];    // ~33.8 KB (W^T chunk, d-major)

    const int tid = threadIdx.x;
    const int cg  = tid & 15;
    const int ng  = tid >> 4;
    const int n0  = ng * 4;
    const int ca  = cg * 4;        // first channel quad
    const int cb  = 64 + cg * 4;   // second channel quad
    const long nbase = (long)blockIdx.x * TILE_N;

    // ---- stage input tile (coalesced float4) ----
    #pragma unroll
    for (int i = 0; i < (TILE_N * EMBED / 4) / 256; ++i) {   // 8 iters
        int idx = tid + i * 256;
        int r = idx >> 5;          // 32 quads per row
        int q = idx & 31;
        long n = nbase + r;
        float4 v = make_float4(0.f, 0.f, 0.f, 0.f);
        if (n < N_NODES) v = ((const float4*)(acc + n * EMBED))[q];
        *(float4*)&s_in[r][q * 4] = v;
    }

    for (int layer = 0; layer < 3; ++layer) {
        const float* W = dw + layer * EMBED * EMBED;
        float racc[4][8];
        #pragma unroll
        for (int k = 0; k < 4; ++k)
            #pragma unroll
            for (int j = 0; j < 8; ++j) racc[k][j] = 0.f;

        for (int dc = 0; dc < EMBED; dc += DCHUNK) {
            __syncthreads();   // protect s_w overwrite / s_in writeback visibility
            // ---- stage W^T chunk: s_w[dd][c] = W[c][dc+dd] ----
            #pragma unroll
            for (int i = 0; i < (DCHUNK * EMBED / 4) / 256; ++i) {  // 8 iters
                int idx = tid + i * 256;
                int c = idx >> 4;          // 16 quads per W row chunk
                int q = idx & 15;
                float4 v = *(const float4*)(W + c * EMBED + dc + q * 4);
                s_w[q*4 + 0][c] = v.x;
                s_w[q*4 + 1][c] = v.y;
                s_w[q*4 + 2][c] = v.z;
                s_w[q*4 + 3][c] = v.w;
            }
            __syncthreads();

            // ---- register-tiled FMA: 32 FMA per dd ----
            #pragma unroll 4
            for (int dd = 0; dd < DCHUNK; ++dd) {
                float4 w0 = *(const float4*)&s_w[dd][ca];
                float4 w1 = *(const float4*)&s_w[dd][cb];
                float wv[8] = {w0.x, w0.y, w0.z, w0.w, w1.x, w1.y, w1.z, w1.w};
                float iv[4];
                #pragma unroll
                for (int k = 0; k < 4; ++k) iv[k] = s_in[n0 + k][dc + dd];
                #pragma unroll
                for (int k = 0; k < 4; ++k)
                    #pragma unroll
                    for (int j = 0; j < 8; ++j)
                        racc[k][j] = fmaf(iv[k], wv[j], racc[k][j]);
            }
        }

        __syncthreads();   // all reads of s_in done before overwrite
        #pragma unroll
        for (int j = 0; j < 8; ++j) {
            int c = (j < 4) ? (ca + j) : (cb + (j - 4));
            float b = db[layer * EMBED + c];
            #pragma unroll
            for (int k = 0; k < 4; ++k)
                s_in[n0 + k][c] = ssp(racc[k][j] + b);
        }
        // next layer's first __syncthreads() covers the writeback
    }

    __syncthreads();
    // ---- stage out_w (12x128) into s_w rows 0..11 ----
    for (int idx = tid; idx < N_OUT * EMBED / 4; idx += 256) {  // 384 quads
        int o = idx >> 5;
        int q = idx & 31;
        float4 v = ((const float4*)ow)[idx];
        *(float4*)&s_w[o][q * 4] = v;
    }
    __syncthreads();

    // ---- output layer: 64 nodes x 12 ----
    for (int item = tid; item < TILE_N * 16; item += 256) {
        int n = item >> 4;
        int o = item & 15;
        if (o < N_OUT) {
            long gn = nbase + n;
            if (gn < N_NODES) {
                float s = 0.f;
                #pragma unroll
                for (int q = 0; q < EMBED / 4; ++q) {
                    float4 a = *(const float4*)&s_in[n][q * 4];
                    float4 b = *(const float4*)&s_w[o][q * 4];
                    s = fmaf(a.x, b.x, s);
                    s = fmaf(a.y, b.y, s);
                    s = fmaf(a.z, b.z, s);
                    s = fmaf(a.w, b.w, s);
                }
                out[gn * N_OUT + o] = s;
            }
        }
    }
}

extern "C" void kernel_launch(void* const* d_in, const int* in_sizes, int n_in,
                              void* d_out, int out_size, void* d_ws, size_t ws_size,
                              hipStream_t stream) {
    const float* m_ji = (const float*)d_in[0];
    const float* rbf  = (const float*)d_in[1];
    const int*   eidx = (const int*)d_in[2];   // [2, N_EDGES]
    const float* wr   = (const float*)d_in[3];
    const float* dw   = (const float*)d_in[4];
    const float* db   = (const float*)d_in[5];
    const float* ow   = (const float*)d_in[6];
    float* out = (float*)d_out;
    float* acc = (float*)d_ws;                 // [N_NODES, EMBED]

    hipMemsetAsync(acc, 0, (size_t)N_NODES * EMBED * sizeof(float), stream);

    edge_kernel<<<N_EDGES / (8 * EK_ITERS), 256, 0, stream>>>(
        rbf, m_ji, eidx + N_EDGES, wr, acc);

    node_kernel<<<(N_NODES + TILE_N - 1) / TILE_N, 256, 0, stream>>>(
        acc, dw, db, ow, out);
}

// Round 3
// 590.378 us; speedup vs baseline: 2.1768x; 2.1768x over previous
//
#include <hip/hip_runtime.h>
#include <math.h>

#define N_NODES 50000
#define N_EDGES 500000
#define EMBED   128
#define RBF_DIM 16
#define N_OUT   12

#define TILE_N   64
#define DCHUNK   32           // d-rows of W^T staged at a time (LDS 50.7KB -> 3 blocks/CU)
#define SPAD     (EMBED + 4)  // padded LDS row stride (floats)

__device__ __forceinline__ float ssp(float x) {
    return fmaxf(x, 0.f) + log1pf(expf(-fabsf(x))) - 0.6931471805599453f;
}

// ---------------- Kernel 1a: build per-node linked list ----------------
__global__ __launch_bounds__(256) void build_ll(
    const int* __restrict__ dst,   // [E]
    int* __restrict__ head,        // [N], pre-set to -1
    int* __restrict__ next)        // [E]
{
    int e = blockIdx.x * 256 + threadIdx.x;
    if (e < N_EDGES) {
        int d = dst[e];
        int old = atomicExch(&head[d], e);
        next[e] = old;
    }
}

// ---------------- Kernel 1b: gather — one wave per node ----------------
// lane owns channels c0 = lane*2, c0+1. No atomics: each node written once.
__global__ __launch_bounds__(256) void gather_kernel(
    const float* __restrict__ m,     // [E,128]
    const float* __restrict__ rbf,   // [E,16]
    const int*   __restrict__ head,  // [N]
    const int*   __restrict__ next,  // [E]
    const float* __restrict__ wr,    // [128,16]
    float* __restrict__ acc)         // [N,128]
{
    const int lane = threadIdx.x & 63;
    const int wave = threadIdx.x >> 6;
    const int n    = blockIdx.x * 4 + wave;
    if (n >= N_NODES) return;
    const int c0 = lane * 2;

    // W rows c0, c0+1 -> 32 registers (reused across all edges of the node)
    float w0[RBF_DIM], w1[RBF_DIM];
    {
        const float4* p0 = (const float4*)(wr + (long)c0 * RBF_DIM);
        const float4* p1 = (const float4*)(wr + (long)(c0 + 1) * RBF_DIM);
        #pragma unroll
        for (int q = 0; q < 4; ++q) {
            float4 a = p0[q], b = p1[q];
            w0[q*4+0]=a.x; w0[q*4+1]=a.y; w0[q*4+2]=a.z; w0[q*4+3]=a.w;
            w1[q*4+0]=b.x; w1[q*4+1]=b.y; w1[q*4+2]=b.z; w1[q*4+3]=b.w;
        }
    }

    float a0 = 0.f, a1 = 0.f;
    int e = __builtin_amdgcn_readfirstlane(head[n]);
    while (e >= 0) {
        float2 mv = *(const float2*)(m + (long)e * EMBED + c0);
        const float4* rp = (const float4*)(rbf + (long)e * RBF_DIM);
        float4 r0 = rp[0], r1 = rp[1], r2 = rp[2], r3 = rp[3];
        float rv[RBF_DIM] = {r0.x,r0.y,r0.z,r0.w, r1.x,r1.y,r1.z,r1.w,
                             r2.x,r2.y,r2.z,r2.w, r3.x,r3.y,r3.z,r3.w};
        float s0 = 0.f, s1 = 0.f;
        #pragma unroll
        for (int r = 0; r < RBF_DIM; ++r) {
            s0 = fmaf(rv[r], w0[r], s0);
            s1 = fmaf(rv[r], w1[r], s1);
        }
        a0 = fmaf(s0, mv.x, a0);
        a1 = fmaf(s1, mv.y, a1);
        e = __builtin_amdgcn_readfirstlane(next[e]);
    }
    float2 o; o.x = a0; o.y = a1;
    *(float2*)(acc + (long)n * EMBED + c0) = o;
}

// ---------------- Kernel 2: fused 3x dense(ssp) + output ----------------
// block = 256 threads; tile = 64 nodes; thread owns 4 nodes x 8 channels.
__global__ __launch_bounds__(256) void node_kernel(
    const float* __restrict__ acc,   // [N,128]
    const float* __restrict__ dw,    // [3,128,128]
    const float* __restrict__ db,    // [3,128]
    const float* __restrict__ ow,    // [12,128]
    float* __restrict__ out)         // [N,12]
{
    __shared__ float s_in[TILE_N][SPAD];   // 33.8 KB
    __shared__ float s_w[DCHUNK][SPAD];    // 16.9 KB

    const int tid = threadIdx.x;
    const int cg  = tid & 15;
    const int ng  = tid >> 4;
    const int n0  = ng * 4;
    const int ca  = cg * 4;
    const int cb  = 64 + cg * 4;
    const long nbase = (long)blockIdx.x * TILE_N;

    // ---- stage input tile (coalesced float4) ----
    #pragma unroll
    for (int i = 0; i < (TILE_N * EMBED / 4) / 256; ++i) {   // 8 iters
        int idx = tid + i * 256;
        int r = idx >> 5;
        int q = idx & 31;
        long n = nbase + r;
        float4 v = make_float4(0.f, 0.f, 0.f, 0.f);
        if (n < N_NODES) v = ((const float4*)(acc + n * EMBED))[q];
        *(float4*)&s_in[r][q * 4] = v;
    }

    for (int layer = 0; layer < 3; ++layer) {
        const float* W = dw + layer * EMBED * EMBED;
        float racc[4][8];
        #pragma unroll
        for (int k = 0; k < 4; ++k)
            #pragma unroll
            for (int j = 0; j < 8; ++j) racc[k][j] = 0.f;

        for (int dc = 0; dc < EMBED; dc += DCHUNK) {
            __syncthreads();
            // ---- stage W^T chunk: s_w[dd][c] = W[c][dc+dd] ----
            #pragma unroll
            for (int i = 0; i < (DCHUNK * EMBED / 4) / 256; ++i) {  // 4 iters
                int idx = tid + i * 256;
                int c = idx >> 3;          // DCHUNK/4 = 8 quads per W-row chunk
                int q = idx & 7;
                float4 v = *(const float4*)(W + c * EMBED + dc + q * 4);
                s_w[q*4 + 0][c] = v.x;
                s_w[q*4 + 1][c] = v.y;
                s_w[q*4 + 2][c] = v.z;
                s_w[q*4 + 3][c] = v.w;
            }
            __syncthreads();

            #pragma unroll 4
            for (int dd = 0; dd < DCHUNK; ++dd) {
                float4 wq0 = *(const float4*)&s_w[dd][ca];
                float4 wq1 = *(const float4*)&s_w[dd][cb];
                float wv[8] = {wq0.x, wq0.y, wq0.z, wq0.w, wq1.x, wq1.y, wq1.z, wq1.w};
                float iv[4];
                #pragma unroll
                for (int k = 0; k < 4; ++k) iv[k] = s_in[n0 + k][dc + dd];
                #pragma unroll
                for (int k = 0; k < 4; ++k)
                    #pragma unroll
                    for (int j = 0; j < 8; ++j)
                        racc[k][j] = fmaf(iv[k], wv[j], racc[k][j]);
            }
        }

        __syncthreads();
        #pragma unroll
        for (int j = 0; j < 8; ++j) {
            int c = (j < 4) ? (ca + j) : (cb + (j - 4));
            float b = db[layer * EMBED + c];
            #pragma unroll
            for (int k = 0; k < 4; ++k)
                s_in[n0 + k][c] = ssp(racc[k][j] + b);
        }
    }

    __syncthreads();
    for (int idx = tid; idx < N_OUT * EMBED / 4; idx += 256) {
        int o = idx >> 5;
        int q = idx & 31;
        float4 v = ((const float4*)ow)[idx];
        *(float4*)&s_w[o][q * 4] = v;
    }
    __syncthreads();

    for (int item = tid; item < TILE_N * 16; item += 256) {
        int n = item >> 4;
        int o = item & 15;
        if (o < N_OUT) {
            long gn = nbase + n;
            if (gn < N_NODES) {
                float s = 0.f;
                #pragma unroll
                for (int q = 0; q < EMBED / 4; ++q) {
                    float4 a = *(const float4*)&s_in[n][q * 4];
                    float4 b = *(const float4*)&s_w[o][q * 4];
                    s = fmaf(a.x, b.x, s);
                    s = fmaf(a.y, b.y, s);
                    s = fmaf(a.z, b.z, s);
                    s = fmaf(a.w, b.w, s);
                }
                out[gn * N_OUT + o] = s;
            }
        }
    }
}

extern "C" void kernel_launch(void* const* d_in, const int* in_sizes, int n_in,
                              void* d_out, int out_size, void* d_ws, size_t ws_size,
                              hipStream_t stream) {
    const float* m_ji = (const float*)d_in[0];
    const float* rbf  = (const float*)d_in[1];
    const int*   eidx = (const int*)d_in[2];   // [2, N_EDGES]
    const float* wr   = (const float*)d_in[3];
    const float* dw   = (const float*)d_in[4];
    const float* db   = (const float*)d_in[5];
    const float* ow   = (const float*)d_in[6];
    float* out = (float*)d_out;

    // workspace layout: head[N] | next[E] | acc[N*EMBED]
    char* ws = (char*)d_ws;
    int*   head = (int*)ws;                                  // 200 KB
    int*   next = (int*)(ws + (size_t)N_NODES * 4);          // 2 MB
    float* acc  = (float*)(ws + (size_t)N_NODES * 4 + (size_t)N_EDGES * 4);  // 25.6 MB

    hipMemsetAsync(head, 0xFF, (size_t)N_NODES * 4, stream);   // head[n] = -1

    build_ll<<<(N_EDGES + 255) / 256, 256, 0, stream>>>(eidx + N_EDGES, head, next);

    gather_kernel<<<(N_NODES + 3) / 4, 256, 0, stream>>>(
        m_ji, rbf, head, next, wr, acc);

    node_kernel<<<(N_NODES + TILE_N - 1) / TILE_N, 256, 0, stream>>>(
        acc, dw, db, ow, out);
}

// Round 9
// 565.620 us; speedup vs baseline: 2.2721x; 1.0438x over previous
//
#include <hip/hip_runtime.h>
#include <math.h>

#define N_NODES 50000
#define N_EDGES 500000
#define EMBED   128
#define RBF_DIM 16
#define N_OUT   12

#define CAP      32           // slots per node bucket (Poisson(10) degree; overflow guarded)
#define OVF_MAX  4096

#define TILE_N   64
#define DCHUNK   32
#define SPAD     (EMBED + 4)

// ws byte offsets: cnt[N] | ovf_cnt | ovf[OVF_MAX] | slot[N*CAP] | acc[N*EMBED]
#define OFF_CNT     0
#define OFF_OVFCNT  200000
#define OFF_OVF     200016
#define OFF_SLOT    216400
#define OFF_ACC     (216400 + (size_t)N_NODES * CAP * 4)   // 6,616,400

// fast shifted-softplus: max(x,0) + log(1 + exp(-|x|)) - log(2)
// __expf/__logf -> v_exp_f32/v_log_f32 (HW transcendentals). Abs error ~1e-6,
// well under the harness tolerance (current absmax 3.9e-3 from fp32 reorder).
__device__ __forceinline__ float ssp(float x) {
    return fmaxf(x, 0.f) + __logf(1.f + __expf(-fabsf(x))) - 0.6931471805599453f;
}

// ---------------- Kernel 1a: bucket fill (CSR without scan) ----------------
__global__ __launch_bounds__(256) void fill_kernel(
    const int* __restrict__ dst,     // [E]
    int* __restrict__ cnt,           // [N], zeroed
    int* __restrict__ slot,          // [N*CAP]
    int* __restrict__ ovf_cnt,       // zeroed
    int* __restrict__ ovf)           // [OVF_MAX]
{
    int e = blockIdx.x * 256 + threadIdx.x;
    if (e < N_EDGES) {
        int d = dst[e];
        int pos = atomicAdd(&cnt[d], 1);
        if (pos < CAP) {
            slot[(long)d * CAP + pos] = e;
        } else {
            int o = atomicAdd(ovf_cnt, 1);
            if (o < OVF_MAX) ovf[o] = e;
        }
    }
}

// ---------------- Kernel 1b: gather — one wave per node, indexed edges ----
// lane owns channels c0 = lane*2, c0+1. No atomics; no pointer chase.
__global__ __launch_bounds__(256) void gather_kernel(
    const float* __restrict__ m,     // [E,128]
    const float* __restrict__ rbf,   // [E,16]
    const int*   __restrict__ cnt,   // [N]
    const int*   __restrict__ slot,  // [N*CAP]
    const float* __restrict__ wr,    // [128,16]
    float* __restrict__ acc)         // [N,128]
{
    const int lane = threadIdx.x & 63;
    const int wave = threadIdx.x >> 6;
    const int n    = blockIdx.x * 4 + wave;
    if (n >= N_NODES) return;
    const int c0 = lane * 2;

    // W rows c0, c0+1 -> 32 registers (reused across all edges of the node)
    float w0[RBF_DIM], w1[RBF_DIM];
    {
        const float4* p0 = (const float4*)(wr + (long)c0 * RBF_DIM);
        const float4* p1 = (const float4*)(wr + (long)(c0 + 1) * RBF_DIM);
        #pragma unroll
        for (int q = 0; q < 4; ++q) {
            float4 a = p0[q], b = p1[q];
            w0[q*4+0]=a.x; w0[q*4+1]=a.y; w0[q*4+2]=a.z; w0[q*4+3]=a.w;
            w1[q*4+0]=b.x; w1[q*4+1]=b.y; w1[q*4+2]=b.z; w1[q*4+3]=b.w;
        }
    }

    int k = cnt[n];
    if (k > CAP) k = CAP;
    const int* sl = slot + (long)n * CAP;

    float a0 = 0.f, a1 = 0.f;
    for (int i = 0; i < k; ++i) {
        int e = __builtin_amdgcn_readfirstlane(sl[i]);
        float2 mv = *(const float2*)(m + (long)e * EMBED + c0);
        const float4* rp = (const float4*)(rbf + (long)e * RBF_DIM);
        float4 r0 = rp[0], r1 = rp[1], r2 = rp[2], r3 = rp[3];
        float rv[RBF_DIM] = {r0.x,r0.y,r0.z,r0.w, r1.x,r1.y,r1.z,r1.w,
                             r2.x,r2.y,r2.z,r2.w, r3.x,r3.y,r3.z,r3.w};
        float s0 = 0.f, s1 = 0.f;
        #pragma unroll
        for (int r = 0; r < RBF_DIM; ++r) {
            s0 = fmaf(rv[r], w0[r], s0);
            s1 = fmaf(rv[r], w1[r], s1);
        }
        a0 = fmaf(s0, mv.x, a0);
        a1 = fmaf(s1, mv.y, a1);
    }
    float2 o; o.x = a0; o.y = a1;
    *(float2*)(acc + (long)n * EMBED + c0) = o;
}

// ---------------- Kernel 1c: overflow cleanup (expected no-op) ----------
__global__ void cleanup_kernel(
    const float* __restrict__ m,
    const float* __restrict__ rbf,
    const float* __restrict__ wr,
    const int*   __restrict__ dst,
    const int*   __restrict__ ovf_cnt,
    const int*   __restrict__ ovf,
    float* __restrict__ acc)
{
    const int c = threadIdx.x;   // 128 threads, channel each
    int k = *ovf_cnt;
    if (k > OVF_MAX) k = OVF_MAX;
    if (k <= 0) return;
    float w[RBF_DIM];
    #pragma unroll
    for (int r = 0; r < RBF_DIM; ++r) w[r] = wr[(long)c * RBF_DIM + r];
    for (int i = 0; i < k; ++i) {
        int e = ovf[i];
        int d = dst[e];
        const float* rp = rbf + (long)e * RBF_DIM;
        float s = 0.f;
        #pragma unroll
        for (int r = 0; r < RBF_DIM; ++r) s = fmaf(w[r], rp[r], s);
        atomicAdd(&acc[(long)d * EMBED + c], s * m[(long)e * EMBED + c]);
    }
}

// ---------------- Kernel 2: fused 3x dense(ssp) + output ----------------
// (identical to round-3 structure; only ssp() body changed to HW transcendentals)
__global__ __launch_bounds__(256) void node_kernel(
    const float* __restrict__ acc,   // [N,128]
    const float* __restrict__ dw,    // [3,128,128]
    const float* __restrict__ db,    // [3,128]
    const float* __restrict__ ow,    // [12,128]
    float* __restrict__ out)         // [N,12]
{
    __shared__ float s_in[TILE_N][SPAD];
    __shared__ float s_w[DCHUNK][SPAD];

    const int tid = threadIdx.x;
    const int cg  = tid & 15;
    const int ng  = tid >> 4;
    const int n0  = ng * 4;
    const int ca  = cg * 4;
    const int cb  = 64 + cg * 4;
    const long nbase = (long)blockIdx.x * TILE_N;

    #pragma unroll
    for (int i = 0; i < (TILE_N * EMBED / 4) / 256; ++i) {
        int idx = tid + i * 256;
        int r = idx >> 5;
        int q = idx & 31;
        long n = nbase + r;
        float4 v = make_float4(0.f, 0.f, 0.f, 0.f);
        if (n < N_NODES) v = ((const float4*)(acc + n * EMBED))[q];
        *(float4*)&s_in[r][q * 4] = v;
    }

    for (int layer = 0; layer < 3; ++layer) {
        const float* W = dw + layer * EMBED * EMBED;
        float racc[4][8];
        #pragma unroll
        for (int k = 0; k < 4; ++k)
            #pragma unroll
            for (int j = 0; j < 8; ++j) racc[k][j] = 0.f;

        for (int dc = 0; dc < EMBED; dc += DCHUNK) {
            __syncthreads();
            #pragma unroll
            for (int i = 0; i < (DCHUNK * EMBED / 4) / 256; ++i) {
                int idx = tid + i * 256;
                int c = idx >> 3;
                int q = idx & 7;
                float4 v = *(const float4*)(W + c * EMBED + dc + q * 4);
                s_w[q*4 + 0][c] = v.x;
                s_w[q*4 + 1][c] = v.y;
                s_w[q*4 + 2][c] = v.z;
                s_w[q*4 + 3][c] = v.w;
            }
            __syncthreads();

            #pragma unroll 4
            for (int dd = 0; dd < DCHUNK; ++dd) {
                float4 wq0 = *(const float4*)&s_w[dd][ca];
                float4 wq1 = *(const float4*)&s_w[dd][cb];
                float wv[8] = {wq0.x, wq0.y, wq0.z, wq0.w, wq1.x, wq1.y, wq1.z, wq1.w};
                float iv[4];
                #pragma unroll
                for (int k = 0; k < 4; ++k) iv[k] = s_in[n0 + k][dc + dd];
                #pragma unroll
                for (int k = 0; k < 4; ++k)
                    #pragma unroll
                    for (int j = 0; j < 8; ++j)
                        racc[k][j] = fmaf(iv[k], wv[j], racc[k][j]);
            }
        }

        __syncthreads();
        #pragma unroll
        for (int j = 0; j < 8; ++j) {
            int c = (j < 4) ? (ca + j) : (cb + (j - 4));
            float b = db[layer * EMBED + c];
            #pragma unroll
            for (int k = 0; k < 4; ++k)
                s_in[n0 + k][c] = ssp(racc[k][j] + b);
        }
    }

    __syncthreads();
    for (int idx = tid; idx < N_OUT * EMBED / 4; idx += 256) {
        int o = idx >> 5;
        int q = idx & 31;
        float4 v = ((const float4*)ow)[idx];
        *(float4*)&s_w[o][q * 4] = v;
    }
    __syncthreads();

    for (int item = tid; item < TILE_N * 16; item += 256) {
        int n = item >> 4;
        int o = item & 15;
        if (o < N_OUT) {
            long gn = nbase + n;
            if (gn < N_NODES) {
                float s = 0.f;
                #pragma unroll
                for (int q = 0; q < EMBED / 4; ++q) {
                    float4 a = *(const float4*)&s_in[n][q * 4];
                    float4 b = *(const float4*)&s_w[o][q * 4];
                    s = fmaf(a.x, b.x, s);
                    s = fmaf(a.y, b.y, s);
                    s = fmaf(a.z, b.z, s);
                    s = fmaf(a.w, b.w, s);
                }
                out[gn * N_OUT + o] = s;
            }
        }
    }
}

extern "C" void kernel_launch(void* const* d_in, const int* in_sizes, int n_in,
                              void* d_out, int out_size, void* d_ws, size_t ws_size,
                              hipStream_t stream) {
    const float* m_ji = (const float*)d_in[0];
    const float* rbf  = (const float*)d_in[1];
    const int*   eidx = (const int*)d_in[2];   // [2, N_EDGES]
    const float* wr   = (const float*)d_in[3];
    const float* dw   = (const float*)d_in[4];
    const float* db   = (const float*)d_in[5];
    const float* ow   = (const float*)d_in[6];
    float* out = (float*)d_out;
    const int* dst = eidx + N_EDGES;

    char* ws = (char*)d_ws;
    int*   cnt     = (int*)(ws + OFF_CNT);
    int*   ovf_cnt = (int*)(ws + OFF_OVFCNT);
    int*   ovf     = (int*)(ws + OFF_OVF);
    int*   slot    = (int*)(ws + OFF_SLOT);
    float* acc     = (float*)(ws + OFF_ACC);

    hipMemsetAsync(ws, 0, OFF_OVF, stream);   // cnt + ovf_cnt = 0

    fill_kernel<<<(N_EDGES + 255) / 256, 256, 0, stream>>>(dst, cnt, slot, ovf_cnt, ovf);

    gather_kernel<<<(N_NODES + 3) / 4, 256, 0, stream>>>(m_ji, rbf, cnt, slot, wr, acc);

    cleanup_kernel<<<1, EMBED, 0, stream>>>(m_ji, rbf, wr, dst, ovf_cnt, ovf, acc);

    node_kernel<<<(N_NODES + TILE_N - 1) / TILE_N, 256, 0, stream>>>(acc, dw, db, ow, out);
}

// Round 10
// 550.199 us; speedup vs baseline: 2.3357x; 1.0280x over previous
//
#include <hip/hip_runtime.h>
#include <math.h>

#define N_NODES 50000
#define N_EDGES 500000
#define EMBED   128
#define RBF_DIM 16
#define N_OUT   12

#define CAP      32           // slots per node bucket (Poisson(10) degree; overflow guarded)
#define OVF_MAX  4096

#define TILE_N   64
#define DCHUNK   32
#define SPAD     (EMBED + 4)

// ws byte offsets: cnt[N] | ovf_cnt | ovf[OVF_MAX] | slot[N*CAP] | acc[N*EMBED]
#define OFF_CNT     0
#define OFF_OVFCNT  200000
#define OFF_OVF     200016
#define OFF_SLOT    216400
#define OFF_ACC     (216400 + (size_t)N_NODES * CAP * 4)   // 6,616,400

// fast shifted-softplus via HW transcendentals (v_exp_f32/v_log_f32)
__device__ __forceinline__ float ssp(float x) {
    return fmaxf(x, 0.f) + __logf(1.f + __expf(-fabsf(x))) - 0.6931471805599453f;
}

// ---------------- Kernel 1a: bucket fill (CSR without scan) ----------------
__global__ __launch_bounds__(256) void fill_kernel(
    const int* __restrict__ dst,     // [E]
    int* __restrict__ cnt,           // [N], zeroed
    int* __restrict__ slot,          // [N*CAP]
    int* __restrict__ ovf_cnt,       // zeroed
    int* __restrict__ ovf)           // [OVF_MAX]
{
    int e = blockIdx.x * 256 + threadIdx.x;
    if (e < N_EDGES) {
        int d = dst[e];
        int pos = atomicAdd(&cnt[d], 1);
        if (pos < CAP) {
            slot[(long)d * CAP + pos] = e;
        } else {
            int o = atomicAdd(ovf_cnt, 1);
            if (o < OVF_MAX) ovf[o] = e;
        }
    }
}

// ---------------- Kernel 1b: gather — one wave per node, 4-edge unroll ----
// lane owns channels c0 = lane*2, c0+1. No atomics; 4 edges' loads in flight.
// rbf/slot addresses are wave-uniform -> scalar loads (SGPR), m rows coalesced.

#define LOAD_EDGE(J) \
    const int e##J = __builtin_amdgcn_readfirstlane(sl[i + J]); \
    const float2 mv##J = *(const float2*)(m + (long)e##J * EMBED + c0); \
    const float4* rq##J = (const float4*)(rbf + (long)e##J * RBF_DIM); \
    const float4 rA##J = rq##J[0], rB##J = rq##J[1], rC##J = rq##J[2], rD##J = rq##J[3];

#define DOT_EDGE(J) { \
    const float rv[RBF_DIM] = {rA##J.x, rA##J.y, rA##J.z, rA##J.w, \
                               rB##J.x, rB##J.y, rB##J.z, rB##J.w, \
                               rC##J.x, rC##J.y, rC##J.z, rC##J.w, \
                               rD##J.x, rD##J.y, rD##J.z, rD##J.w}; \
    float s0 = 0.f, s1 = 0.f; \
    _Pragma("unroll") \
    for (int r = 0; r < RBF_DIM; ++r) { \
        s0 = fmaf(rv[r], w0[r], s0); \
        s1 = fmaf(rv[r], w1[r], s1); \
    } \
    a0 = fmaf(s0, mv##J.x, a0); \
    a1 = fmaf(s1, mv##J.y, a1); }

__global__ __launch_bounds__(256) void gather_kernel(
    const float* __restrict__ m,     // [E,128]
    const float* __restrict__ rbf,   // [E,16]
    const int*   __restrict__ cnt,   // [N]
    const int*   __restrict__ slot,  // [N*CAP]
    const float* __restrict__ wr,    // [128,16]
    float* __restrict__ acc)         // [N,128]
{
    const int lane = threadIdx.x & 63;
    const int wave = threadIdx.x >> 6;
    const int n    = blockIdx.x * 4 + wave;
    if (n >= N_NODES) return;
    const int c0 = lane * 2;

    // W rows c0, c0+1 -> 32 registers (reused across all edges of the node)
    float w0[RBF_DIM], w1[RBF_DIM];
    {
        const float4* p0 = (const float4*)(wr + (long)c0 * RBF_DIM);
        const float4* p1 = (const float4*)(wr + (long)(c0 + 1) * RBF_DIM);
        #pragma unroll
        for (int q = 0; q < 4; ++q) {
            float4 a = p0[q], b = p1[q];
            w0[q*4+0]=a.x; w0[q*4+1]=a.y; w0[q*4+2]=a.z; w0[q*4+3]=a.w;
            w1[q*4+0]=b.x; w1[q*4+1]=b.y; w1[q*4+2]=b.z; w1[q*4+3]=b.w;
        }
    }

    int k = cnt[n];
    if (k > CAP) k = CAP;
    const int* sl = slot + (long)n * CAP;

    float a0 = 0.f, a1 = 0.f;
    int i = 0;
    for (; i + 4 <= k; i += 4) {
        // issue all loads for 4 edges before consuming any (4x MLP)
        LOAD_EDGE(0)
        LOAD_EDGE(1)
        LOAD_EDGE(2)
        LOAD_EDGE(3)
        DOT_EDGE(0)
        DOT_EDGE(1)
        DOT_EDGE(2)
        DOT_EDGE(3)
    }
    for (; i < k; ++i) {
        const int e = __builtin_amdgcn_readfirstlane(sl[i]);
        const float2 mv = *(const float2*)(m + (long)e * EMBED + c0);
        const float4* rq = (const float4*)(rbf + (long)e * RBF_DIM);
        const float4 rA = rq[0], rB = rq[1], rC = rq[2], rD = rq[3];
        const float rv[RBF_DIM] = {rA.x,rA.y,rA.z,rA.w, rB.x,rB.y,rB.z,rB.w,
                                   rC.x,rC.y,rC.z,rC.w, rD.x,rD.y,rD.z,rD.w};
        float s0 = 0.f, s1 = 0.f;
        #pragma unroll
        for (int r = 0; r < RBF_DIM; ++r) {
            s0 = fmaf(rv[r], w0[r], s0);
            s1 = fmaf(rv[r], w1[r], s1);
        }
        a0 = fmaf(s0, mv.x, a0);
        a1 = fmaf(s1, mv.y, a1);
    }
    float2 o; o.x = a0; o.y = a1;
    *(float2*)(acc + (long)n * EMBED + c0) = o;
}

// ---------------- Kernel 1c: overflow cleanup (expected no-op) ----------
__global__ void cleanup_kernel(
    const float* __restrict__ m,
    const float* __restrict__ rbf,
    const float* __restrict__ wr,
    const int*   __restrict__ dst,
    const int*   __restrict__ ovf_cnt,
    const int*   __restrict__ ovf,
    float* __restrict__ acc)
{
    const int c = threadIdx.x;   // 128 threads, channel each
    int k = *ovf_cnt;
    if (k > OVF_MAX) k = OVF_MAX;
    if (k <= 0) return;
    float w[RBF_DIM];
    #pragma unroll
    for (int r = 0; r < RBF_DIM; ++r) w[r] = wr[(long)c * RBF_DIM + r];
    for (int i = 0; i < k; ++i) {
        int e = ovf[i];
        int d = dst[e];
        const float* rp = rbf + (long)e * RBF_DIM;
        float s = 0.f;
        #pragma unroll
        for (int r = 0; r < RBF_DIM; ++r) s = fmaf(w[r], rp[r], s);
        atomicAdd(&acc[(long)d * EMBED + c], s * m[(long)e * EMBED + c]);
    }
}

// ---------------- Kernel 2: fused 3x dense(ssp) + output (UNCHANGED) -----
__global__ __launch_bounds__(256) void node_kernel(
    const float* __restrict__ acc,   // [N,128]
    const float* __restrict__ dw,    // [3,128,128]
    const float* __restrict__ db,    // [3,128]
    const float* __restrict__ ow,    // [12,128]
    float* __restrict__ out)         // [N,12]
{
    __shared__ float s_in[TILE_N][SPAD];
    __shared__ float s_w[DCHUNK][SPAD];

    const int tid = threadIdx.x;
    const int cg  = tid & 15;
    const int ng  = tid >> 4;
    const int n0  = ng * 4;
    const int ca  = cg * 4;
    const int cb  = 64 + cg * 4;
    const long nbase = (long)blockIdx.x * TILE_N;

    #pragma unroll
    for (int i = 0; i < (TILE_N * EMBED / 4) / 256; ++i) {
        int idx = tid + i * 256;
        int r = idx >> 5;
        int q = idx & 31;
        long n = nbase + r;
        float4 v = make_float4(0.f, 0.f, 0.f, 0.f);
        if (n < N_NODES) v = ((const float4*)(acc + n * EMBED))[q];
        *(float4*)&s_in[r][q * 4] = v;
    }

    for (int layer = 0; layer < 3; ++layer) {
        const float* W = dw + layer * EMBED * EMBED;
        float racc[4][8];
        #pragma unroll
        for (int k = 0; k < 4; ++k)
            #pragma unroll
            for (int j = 0; j < 8; ++j) racc[k][j] = 0.f;

        for (int dc = 0; dc < EMBED; dc += DCHUNK) {
            __syncthreads();
            #pragma unroll
            for (int i = 0; i < (DCHUNK * EMBED / 4) / 256; ++i) {
                int idx = tid + i * 256;
                int c = idx >> 3;
                int q = idx & 7;
                float4 v = *(const float4*)(W + c * EMBED + dc + q * 4);
                s_w[q*4 + 0][c] = v.x;
                s_w[q*4 + 1][c] = v.y;
                s_w[q*4 + 2][c] = v.z;
                s_w[q*4 + 3][c] = v.w;
            }
            __syncthreads();

            #pragma unroll 4
            for (int dd = 0; dd < DCHUNK; ++dd) {
                float4 wq0 = *(const float4*)&s_w[dd][ca];
                float4 wq1 = *(const float4*)&s_w[dd][cb];
                float wv[8] = {wq0.x, wq0.y, wq0.z, wq0.w, wq1.x, wq1.y, wq1.z, wq1.w};
                float iv[4];
                #pragma unroll
                for (int k = 0; k < 4; ++k) iv[k] = s_in[n0 + k][dc + dd];
                #pragma unroll
                for (int k = 0; k < 4; ++k)
                    #pragma unroll
                    for (int j = 0; j < 8; ++j)
                        racc[k][j] = fmaf(iv[k], wv[j], racc[k][j]);
            }
        }

        __syncthreads();
        #pragma unroll
        for (int j = 0; j < 8; ++j) {
            int c = (j < 4) ? (ca + j) : (cb + (j - 4));
            float b = db[layer * EMBED + c];
            #pragma unroll
            for (int k = 0; k < 4; ++k)
                s_in[n0 + k][c] = ssp(racc[k][j] + b);
        }
    }

    __syncthreads();
    for (int idx = tid; idx < N_OUT * EMBED / 4; idx += 256) {
        int o = idx >> 5;
        int q = idx & 31;
        float4 v = ((const float4*)ow)[idx];
        *(float4*)&s_w[o][q * 4] = v;
    }
    __syncthreads();

    for (int item = tid; item < TILE_N * 16; item += 256) {
        int n = item >> 4;
        int o = item & 15;
        if (o < N_OUT) {
            long gn = nbase + n;
            if (gn < N_NODES) {
                float s = 0.f;
                #pragma unroll
                for (int q = 0; q < EMBED / 4; ++q) {
                    float4 a = *(const float4*)&s_in[n][q * 4];
                    float4 b = *(const float4*)&s_w[o][q * 4];
                    s = fmaf(a.x, b.x, s);
                    s = fmaf(a.y, b.y, s);
                    s = fmaf(a.z, b.z, s);
                    s = fmaf(a.w, b.w, s);
                }
                out[gn * N_OUT + o] = s;
            }
        }
    }
}

extern "C" void kernel_launch(void* const* d_in, const int* in_sizes, int n_in,
                              void* d_out, int out_size, void* d_ws, size_t ws_size,
                              hipStream_t stream) {
    const float* m_ji = (const float*)d_in[0];
    const float* rbf  = (const float*)d_in[1];
    const int*   eidx = (const int*)d_in[2];   // [2, N_EDGES]
    const float* wr   = (const float*)d_in[3];
    const float* dw   = (const float*)d_in[4];
    const float* db   = (const float*)d_in[5];
    const float* ow   = (const float*)d_in[6];
    float* out = (float*)d_out;
    const int* dst = eidx + N_EDGES;

    char* ws = (char*)d_ws;
    int*   cnt     = (int*)(ws + OFF_CNT);
    int*   ovf_cnt = (int*)(ws + OFF_OVFCNT);
    int*   ovf     = (int*)(ws + OFF_OVF);
    int*   slot    = (int*)(ws + OFF_SLOT);
    float* acc     = (float*)(ws + OFF_ACC);

    hipMemsetAsync(ws, 0, OFF_OVF, stream);   // cnt + ovf_cnt = 0

    fill_kernel<<<(N_EDGES + 255) / 256, 256, 0, stream>>>(dst, cnt, slot, ovf_cnt, ovf);

    gather_kernel<<<(N_NODES + 3) / 4, 256, 0, stream>>>(m_ji, rbf, cnt, slot, wr, acc);

    cleanup_kernel<<<1, EMBED, 0, stream>>>(m_ji, rbf, wr, dst, ovf_cnt, ovf, acc);

    node_kernel<<<(N_NODES + TILE_N - 1) / TILE_N, 256, 0, stream>>>(acc, dw, db, ow, out);
}